// Round 1
// baseline (1060.390 us; speedup 1.0000x reference)
//
#include <hip/hip_runtime.h>
#include <math.h>

// Problem constants (fixed by setup_inputs)
#define FEATN 128
#define NRBF  20
#define NCG   2000
#define CUTF  5.0f
#define PI_F  3.14159265358979323846f

// LDS row stride in bf16 units: 128 + 8 pad (16B-aligned, breaks bank conflicts)
#define LSTR 136

typedef __attribute__((ext_vector_type(8))) short bf16x8;
typedef __attribute__((ext_vector_type(4))) float f32x4;

__device__ inline unsigned short f2bf(float x) {
    unsigned int u = __float_as_uint(x);
    u += 0x7fffu + ((u >> 16) & 1u);
    return (unsigned short)(u >> 16);
}

// ---------------- weight packing ----------------
// B-fragment layout for mfma_f32_16x16x32_bf16:
//   lane holds B[k][n] with n = nt*16 + (lane&15), k = kt*32 + (lane>>4)*8 + j, j=0..7
// packed flat: (((kt*NT + nt)*64 + lane)*8 + j)
#define W1P_ELEMS (4*8*64*8)    // 16384
#define W2P_ELEMS (4*24*64*8)   // 49152
#define WRP_ELEMS (24*64*8)     // 12288  (K padded 20->32, single kt)

__global__ void pack_weights(const float* __restrict__ W1,
                             const float* __restrict__ W2,
                             const float* __restrict__ Wr,
                             short* __restrict__ W1p,
                             short* __restrict__ W2p,
                             short* __restrict__ Wrp) {
    int t = blockIdx.x * blockDim.x + threadIdx.x;
    if (t < W1P_ELEMS) {
        int j = t & 7, lane = (t >> 3) & 63, tile = t >> 9; // tile = kt*8+nt
        int nt = tile & 7, kt = tile >> 3;
        int k = kt * 32 + (lane >> 4) * 8 + j;
        int n = nt * 16 + (lane & 15);
        W1p[t] = (short)f2bf(W1[k * 128 + n]);
        return;
    }
    t -= W1P_ELEMS;
    if (t < W2P_ELEMS) {
        int j = t & 7, lane = (t >> 3) & 63, tile = t >> 9; // tile = kt*24+nt
        int nt = tile % 24, kt = tile / 24;
        int k = kt * 32 + (lane >> 4) * 8 + j;
        int n = nt * 16 + (lane & 15);
        W2p[t] = (short)f2bf(W2[k * 384 + n]);
        return;
    }
    t -= W2P_ELEMS;
    if (t < WRP_ELEMS) {
        int j = t & 7, lane = (t >> 3) & 63, nt = t >> 9; // 0..23
        int k = (lane >> 4) * 8 + j;
        int n = nt * 16 + (lane & 15);
        float v = (k < NRBF) ? Wr[k * 384 + n] : 0.0f;
        Wrp[t] = (short)f2bf(v);
    }
}

// ---------------- counting sort by segment ----------------
__global__ void hist_kernel(const int* __restrict__ mapping,
                            int* __restrict__ counts, int E) {
    int t = blockIdx.x * blockDim.x + threadIdx.x;
    if (t < E) atomicAdd(&counts[mapping[t]], 1);
}

// one block of 64 threads; 64*32 = 2048 >= NCG
__global__ void scan_kernel(const int* __restrict__ counts,
                            int* __restrict__ start,
                            int* __restrict__ cursor) {
    int lane = threadIdx.x;          // 0..63
    int base = lane * 32;
    int loc[32];
    int s = 0;
#pragma unroll
    for (int j = 0; j < 32; ++j) {
        int idx = base + j;
        int c = (idx < NCG) ? counts[idx] : 0;
        loc[j] = s;
        s += c;
    }
    int inc = s;
#pragma unroll
    for (int off = 1; off < 64; off <<= 1) {
        int n = __shfl_up(inc, off, 64);
        if (lane >= off) inc += n;
    }
    int excl = inc - s;
#pragma unroll
    for (int j = 0; j < 32; ++j) {
        int idx = base + j;
        if (idx < NCG) {
            start[idx]  = excl + loc[j];
            cursor[idx] = excl + loc[j];
        }
    }
}

__global__ void scatter_kernel(const int* __restrict__ mapping,
                               int* __restrict__ cursor,
                               int* __restrict__ order, int E) {
    int t = blockIdx.x * blockDim.x + threadIdx.x;
    if (t < E) {
        int seg = mapping[t];
        int pos = atomicAdd(&cursor[seg], 1);
        order[pos] = t;
    }
}

// ---------------- main fused kernel: one block per segment ----------------
// 64 edges/tile, 4 waves; wave w owns rows [w*16, w*16+16) of EVERYTHING:
// S/H tile rows, geometry rows, accumulator region. => the tile loop is
// barrier-free (waves are 4 independent pipelines; intra-wave LDS ordering
// is program order). Next tile's order/s_i/r_iI loads are issued at the top
// of the current tile's compute and converted/written to LDS after the a2
// fragments are consumed. v_i gathers in the ft loop are ping-pong
// prefetched one iteration ahead. b2/br live in LDS.
__global__ __launch_bounds__(256, 4) void
main_kernel(const float* __restrict__ s_i, const float* __restrict__ v_i,
            const float* __restrict__ r_iI, const float* __restrict__ b1,
            const float* __restrict__ b2, const float* __restrict__ br,
            const int* __restrict__ order, const int* __restrict__ start,
            const int* __restrict__ counts,
            const short* __restrict__ W1p, const short* __restrict__ W2p,
            const short* __restrict__ Wrp,
            float* __restrict__ out) {
    __shared__ __align__(16) short lds_sh[64 * LSTR];   // S tile, then H tile (wave-private rows)
    __shared__ float lds_acc[4 * 512];     // per-wave accumulators: [s:128][v:384]
    __shared__ float lds_bias[768];        // b2[0:384] br[384:768]
    __shared__ int   lds_eid[2][64];       // double-buffered, wave-private rows
    __shared__ float lds_dist[2][64];
    __shared__ float lds_env[2][64];
    __shared__ float lds_unit[2][64][3];

    const int tid  = threadIdx.x;
    const int lane = tid & 63;
    const int w    = tid >> 6;       // wave 0..3
    const int lq   = lane >> 4;      // quad 0..3
    const int lc   = lane & 15;
    const int seg  = blockIdx.x;

    const int st  = start[seg];
    const int cnt = counts[seg];

    // staging assignment: 4 lanes per row, wave-private rows
    const int  R   = w * 16 + (lane >> 2);   // global tile row this thread stages
    const int  sq  = lane & 3;               // quarter of the row
    const bool geo = (lane < 16);            // geometry lanes
    const int  G   = w * 16 + (lane & 15);   // geometry row (valid when geo)

    // zero per-wave accumulators + stage biases (only cross-wave init)
    for (int i = tid; i < 4 * 512; i += 256) lds_acc[i] = 0.0f;
    for (int i = tid; i < 768; i += 256) lds_bias[i] = (i < 384) ? b2[i] : br[i - 384];

    // hoist b1
    float b1v[8];
#pragma unroll
    for (int nt = 0; nt < 8; ++nt) b1v[nt] = b1[nt * 16 + lc];

    const bf16x8* W1f = reinterpret_cast<const bf16x8*>(W1p);
    const bf16x8* W2f = reinterpret_cast<const bf16x8*>(W2p);
    const bf16x8* Wrf = reinterpret_cast<const bf16x8*>(Wrp);

    __syncthreads();   // lds_acc + lds_bias visible to all; ONLY barrier before epilogue

    const int nT = (cnt + 63) >> 6;

    // persistent staging registers (tile t+1 in flight during tile t)
    float4 sp[8];
    int eg = 0; float gx = 0.f, gy = 0.f, gz = 0.f;

    // ---- prologue: stage tile 0 ----
    if (nT > 0) {
        const int valid0 = min(64, cnt);
        {
            const int e0 = order[st + min(R, valid0 - 1)];
            const float4* src = reinterpret_cast<const float4*>(
                s_i + (size_t)e0 * FEATN + sq * 32);
#pragma unroll
            for (int c = 0; c < 8; ++c) sp[c] = src[c];
        }
        if (geo) {
            eg = order[st + min(G, valid0 - 1)];
            gx = r_iI[(size_t)eg * 3 + 0];
            gy = r_iI[(size_t)eg * 3 + 1];
            gz = r_iI[(size_t)eg * 3 + 2];
        }
        {
            short* dst = lds_sh + R * LSTR + sq * 32;
#pragma unroll
            for (int c = 0; c < 8; ++c) {
                float4 v = sp[c];
                unsigned int p0 = (unsigned int)f2bf(v.x) | ((unsigned int)f2bf(v.y) << 16);
                unsigned int p1 = (unsigned int)f2bf(v.z) | ((unsigned int)f2bf(v.w) << 16);
                *reinterpret_cast<uint2*>(dst + c * 4) = make_uint2(p0, p1);
            }
        }
        if (geo) {
            float d = sqrtf(gx * gx + gy * gy + gz * gz + 3e-8f);
            float inv_d = 1.0f / d;
            lds_dist[0][G] = d;
            lds_unit[0][G][0] = gx * inv_d;
            lds_unit[0][G][1] = gy * inv_d;
            lds_unit[0][G][2] = gz * inv_d;
            float env = (d < CUTF) ? 0.5f * (__cosf(PI_F * d / CUTF) + 1.0f) : 0.0f;
            lds_env[0][G] = (G < valid0) ? env : 0.0f;
            lds_eid[0][G] = eg;
        }
    }

    for (int t = 0; t < nT; ++t) {
        const int p = t & 1;

        // ---- A: GEMM1 A-fragments from current S tile ----
        bf16x8 a1[4];
#pragma unroll
        for (int kt = 0; kt < 4; ++kt)
            a1[kt] = *reinterpret_cast<const bf16x8*>(
                lds_sh + (w * 16 + lc) * LSTR + kt * 32 + lq * 8);

        // ---- B: issue next-tile prefetch (order -> s_i rows, r_iI) ----
        const bool pf = (t + 1 < nT);
        int validn = 0;
        if (pf) {
            validn = min(64, cnt - (t + 1) * 64);
            const int basen = st + (t + 1) * 64;
            const int e1 = order[basen + min(R, validn - 1)];
            const float4* src = reinterpret_cast<const float4*>(
                s_i + (size_t)e1 * FEATN + sq * 32);
#pragma unroll
            for (int c = 0; c < 8; ++c) sp[c] = src[c];
            if (geo) {
                eg = order[basen + min(G, validn - 1)];
                gx = r_iI[(size_t)eg * 3 + 0];
                gy = r_iI[(size_t)eg * 3 + 1];
                gz = r_iI[(size_t)eg * 3 + 2];
            }
        }

        // ---- C: GEMM1: H = silu(S @ W1 + b1), written in-place (wave-private rows) ----
#pragma unroll
        for (int nt = 0; nt < 8; ++nt) {
            f32x4 acc = {0.f, 0.f, 0.f, 0.f};
#pragma unroll
            for (int kt = 0; kt < 4; ++kt)
                acc = __builtin_amdgcn_mfma_f32_16x16x32_bf16(
                    a1[kt], W1f[(kt * 8 + nt) * 64 + lane], acc, 0, 0, 0);
#pragma unroll
            for (int i = 0; i < 4; ++i) {
                float x = acc[i] + b1v[nt];
                float h = x / (1.0f + __expf(-x));
                lds_sh[(w * 16 + lq * 4 + i) * LSTR + nt * 16 + lc] = (short)f2bf(h);
            }
        }

        // ---- D: GEMM2 A-fragments, rbf fragment, per-row geometry regs ----
        bf16x8 a2[4];
#pragma unroll
        for (int kt = 0; kt < 4; ++kt)
            a2[kt] = *reinterpret_cast<const bf16x8*>(
                lds_sh + (w * 16 + lc) * LSTR + kt * 32 + lq * 8);

        bf16x8 rb;
        {
            float d = lds_dist[p][w * 16 + lc];
            float inv_d = 1.0f / d;
            float x0 = PI_F * d / CUTF;
#pragma unroll
            for (int j = 0; j < 8; ++j) {
                int k = lq * 8 + j;
                float v = 0.0f;
                if (k < NRBF) v = __sinf((float)(k + 1) * x0) * inv_d;
                rb[j] = (short)f2bf(v);
            }
        }

        float envi[4], ux[4], uy[4], uz[4];
        unsigned voff[4];
#pragma unroll
        for (int i = 0; i < 4; ++i) {
            const int e = w * 16 + lq * 4 + i;
            envi[i] = lds_env[p][e];
            ux[i] = lds_unit[p][e][0];
            uy[i] = lds_unit[p][e][1];
            uz[i] = lds_unit[p][e][2];
            voff[i] = (unsigned)lds_eid[p][e] * 1536u;   // byte offset into v_i
        }

        // ---- F: convert+write next S tile (a2 consumed; rows wave-private),
        //         finish next-tile geometry ----
        if (pf) {
            short* dst = lds_sh + R * LSTR + sq * 32;
#pragma unroll
            for (int c = 0; c < 8; ++c) {
                float4 v = sp[c];
                unsigned int p0 = (unsigned int)f2bf(v.x) | ((unsigned int)f2bf(v.y) << 16);
                unsigned int p1 = (unsigned int)f2bf(v.z) | ((unsigned int)f2bf(v.w) << 16);
                *reinterpret_cast<uint2*>(dst + c * 4) = make_uint2(p0, p1);
            }
            if (geo) {
                float d = sqrtf(gx * gx + gy * gy + gz * gz + 3e-8f);
                float inv_d = 1.0f / d;
                const int pn = p ^ 1;
                lds_dist[pn][G] = d;
                lds_unit[pn][G][0] = gx * inv_d;
                lds_unit[pn][G][1] = gy * inv_d;
                lds_unit[pn][G][2] = gz * inv_d;
                float env = (d < CUTF) ? 0.5f * (__cosf(PI_F * d / CUTF) + 1.0f) : 0.0f;
                lds_env[pn][G] = (G < validn) ? env : 0.0f;
                lds_eid[pn][G] = eg;
            }
        }

        // ---- E: GEMM2 + RBF + epilogue, v_i ping-pong prefetch ----
        float* aw = lds_acc + w * 512;

#define LOADV(VX, VY, VZ, ftv)                                               \
        if ((ftv) < 8) {                                                     \
            const int f_ = (ftv) * 16 + lc;                                  \
            _Pragma("unroll")                                                \
            for (int i_ = 0; i_ < 4; ++i_) {                                 \
                const float* vp_ = (const float*)((const char*)v_i +         \
                                                  voff[i_] + f_ * 12);       \
                VX[i_] = vp_[0]; VY[i_] = vp_[1]; VZ[i_] = vp_[2];           \
            }                                                                \
        }

#define FTBODY(ftv, VX, VY, VZ) {                                            \
            const int ft_ = (ftv);                                           \
            f32x4 acc0 = {0.f,0.f,0.f,0.f}, acc1 = {0.f,0.f,0.f,0.f},        \
                  acc2 = {0.f,0.f,0.f,0.f};                                  \
            __builtin_amdgcn_s_setprio(1);                                   \
            _Pragma("unroll")                                                \
            for (int kt_ = 0; kt_ < 4; ++kt_) {                              \
                bf16x8 a_ = a2[kt_];                                         \
                acc0 = __builtin_amdgcn_mfma_f32_16x16x32_bf16(              \
                    a_, W2f[(kt_ * 24 + ft_     ) * 64 + lane], acc0, 0,0,0);\
                acc1 = __builtin_amdgcn_mfma_f32_16x16x32_bf16(              \
                    a_, W2f[(kt_ * 24 + ft_ +  8) * 64 + lane], acc1, 0,0,0);\
                acc2 = __builtin_amdgcn_mfma_f32_16x16x32_bf16(              \
                    a_, W2f[(kt_ * 24 + ft_ + 16) * 64 + lane], acc2, 0,0,0);\
            }                                                                \
            f32x4 z4 = {0.f,0.f,0.f,0.f};                                    \
            f32x4 wa0 = __builtin_amdgcn_mfma_f32_16x16x32_bf16(             \
                rb, Wrf[(ft_     ) * 64 + lane], z4, 0, 0, 0);               \
            f32x4 wa1 = __builtin_amdgcn_mfma_f32_16x16x32_bf16(             \
                rb, Wrf[(ft_ +  8) * 64 + lane], z4, 0, 0, 0);               \
            f32x4 wa2 = __builtin_amdgcn_mfma_f32_16x16x32_bf16(             \
                rb, Wrf[(ft_ + 16) * 64 + lane], z4, 0, 0, 0);               \
            __builtin_amdgcn_s_setprio(0);                                   \
            const int f_ = ft_ * 16 + lc;                                    \
            float b2v0 = lds_bias[f_], b2v1 = lds_bias[128 + f_],            \
                  b2v2 = lds_bias[256 + f_];                                 \
            float brv0 = lds_bias[384 + f_], brv1 = lds_bias[512 + f_],      \
                  brv2 = lds_bias[640 + f_];                                 \
            float sds = 0.f, svx = 0.f, svy = 0.f, svz = 0.f;                \
            _Pragma("unroll")                                                \
            for (int i_ = 0; i_ < 4; ++i_) {                                 \
                float phi0 = acc0[i_] + b2v0;                                \
                float phi1 = acc1[i_] + b2v1;                                \
                float phi2 = acc2[i_] + b2v2;                                \
                float w0 = (wa0[i_] + brv0) * envi[i_];                      \
                float w1 = (wa1[i_] + brv1) * envi[i_];                      \
                float w2 = (wa2[i_] + brv2) * envi[i_];                      \
                float inv0 = phi0 * w0;                                      \
                float inv1 = phi1 * w1;                                      \
                float inv2 = phi2 * w2;                                      \
                sds += inv1;                                                 \
                svx += inv2 * ux[i_] + inv0 * VX[i_];                        \
                svy += inv2 * uy[i_] + inv0 * VY[i_];                        \
                svz += inv2 * uz[i_] + inv0 * VZ[i_];                        \
            }                                                                \
            sds += __shfl_xor(sds, 16); sds += __shfl_xor(sds, 32);          \
            svx += __shfl_xor(svx, 16); svx += __shfl_xor(svx, 32);          \
            svy += __shfl_xor(svy, 16); svy += __shfl_xor(svy, 32);          \
            svz += __shfl_xor(svz, 16); svz += __shfl_xor(svz, 32);          \
            if (lq == 0) {                                                   \
                aw[f_]               += sds;                                 \
                aw[128 + f_ * 3 + 0] += svx;                                 \
                aw[128 + f_ * 3 + 1] += svy;                                 \
                aw[128 + f_ * 3 + 2] += svz;                                 \
            }                                                                \
        }

        float vAx[4], vAy[4], vAz[4], vBx[4], vBy[4], vBz[4];
        LOADV(vAx, vAy, vAz, 0)
#pragma unroll 1
        for (int fp = 0; fp < 4; ++fp) {
            const int ft0 = fp * 2;
            LOADV(vBx, vBy, vBz, ft0 + 1)
            FTBODY(ft0, vAx, vAy, vAz)
            LOADV(vAx, vAy, vAz, ft0 + 2)
            FTBODY(ft0 + 1, vBx, vBy, vBz)
        }
#undef LOADV
#undef FTBODY
    }
    __syncthreads();

    // ---- final: cross-wave reduce, mean, write out ----
    const float invc = (cnt > 0) ? (1.0f / (float)cnt) : 0.0f;
    const int NS = NCG * 128;
    for (int o = tid; o < 512; o += 256) {
        float v = lds_acc[o] + lds_acc[512 + o] + lds_acc[1024 + o] + lds_acc[1536 + o];
        v *= invc;
        if (o < 128) out[(size_t)seg * 128 + o] = v;
        else         out[NS + (size_t)seg * 384 + (o - 128)] = v;
    }
}

extern "C" void kernel_launch(void* const* d_in, const int* in_sizes, int n_in,
                              void* d_out, int out_size, void* d_ws, size_t ws_size,
                              hipStream_t stream) {
    const float* s_i  = (const float*)d_in[0];
    const float* v_i  = (const float*)d_in[1];
    const float* r_iI = (const float*)d_in[2];
    const float* W1   = (const float*)d_in[3];
    const float* b1   = (const float*)d_in[4];
    const float* W2   = (const float*)d_in[5];
    const float* b2   = (const float*)d_in[6];
    const float* Wr   = (const float*)d_in[7];
    const float* br   = (const float*)d_in[8];
    const int* mapping = (const int*)d_in[9];
    // d_in[10] = num_cg (compile-time NCG=2000)

    const int E = in_sizes[0] / FEATN;   // 200000

    char* ws = (char*)d_ws;
    int*   counts = (int*)(ws + 0);          //  8,000 B
    int*   start  = (int*)(ws + 8192);       //  8,000 B
    int*   cursor = (int*)(ws + 16384);      //  8,000 B
    int*   order  = (int*)(ws + 24576);      // 800,000 B
    short* W1p    = (short*)(ws + 829440);   // 32,768 B
    short* W2p    = (short*)(ws + 862208);   // 98,304 B
    short* Wrp    = (short*)(ws + 960512);   // 24,576 B

    hipMemsetAsync(counts, 0, NCG * sizeof(int), stream);
    pack_weights<<<(W1P_ELEMS + W2P_ELEMS + WRP_ELEMS) / 256, 256, 0, stream>>>(
        W1, W2, Wr, W1p, W2p, Wrp);
    hist_kernel<<<(E + 255) / 256, 256, 0, stream>>>(mapping, counts, E);
    scan_kernel<<<1, 64, 0, stream>>>(counts, start, cursor);
    scatter_kernel<<<(E + 255) / 256, 256, 0, stream>>>(mapping, cursor, order, E);
    main_kernel<<<NCG, 256, 0, stream>>>(s_i, v_i, r_iI, b1, b2, br,
                                         order, start, counts,
                                         W1p, W2p, Wrp, (float*)d_out);
}

// Round 4
// 943.899 us; speedup vs baseline: 1.1234x; 1.1234x over previous
//
#include <hip/hip_runtime.h>
#include <math.h>

// Problem constants (fixed by setup_inputs)
#define FEATN 128
#define NRBF  20
#define NCG   2000
#define CUTF  5.0f
#define PI_F  3.14159265358979323846f

// LDS row stride in bf16 units: 128 + 8 pad (16B-aligned, breaks bank conflicts)
#define LSTR 136

typedef __attribute__((ext_vector_type(8))) short bf16x8;
typedef __attribute__((ext_vector_type(4))) float f32x4;

__device__ inline unsigned short f2bf(float x) {
    unsigned int u = __float_as_uint(x);
    u += 0x7fffu + ((u >> 16) & 1u);
    return (unsigned short)(u >> 16);
}

// ---------------- weight packing ----------------
// B-fragment layout for mfma_f32_16x16x32_bf16:
//   lane holds B[k][n] with n = nt*16 + (lane&15), k = kt*32 + (lane>>4)*8 + j, j=0..7
// packed flat: (((kt*NT + nt)*64 + lane)*8 + j)
#define W1P_ELEMS (4*8*64*8)    // 16384
#define W2P_ELEMS (4*24*64*8)   // 49152
#define WRP_ELEMS (24*64*8)     // 12288  (K padded 20->32, single kt)

__global__ void pack_weights(const float* __restrict__ W1,
                             const float* __restrict__ W2,
                             const float* __restrict__ Wr,
                             short* __restrict__ W1p,
                             short* __restrict__ W2p,
                             short* __restrict__ Wrp) {
    int t = blockIdx.x * blockDim.x + threadIdx.x;
    if (t < W1P_ELEMS) {
        int j = t & 7, lane = (t >> 3) & 63, tile = t >> 9; // tile = kt*8+nt
        int nt = tile & 7, kt = tile >> 3;
        int k = kt * 32 + (lane >> 4) * 8 + j;
        int n = nt * 16 + (lane & 15);
        W1p[t] = (short)f2bf(W1[k * 128 + n]);
        return;
    }
    t -= W1P_ELEMS;
    if (t < W2P_ELEMS) {
        int j = t & 7, lane = (t >> 3) & 63, tile = t >> 9; // tile = kt*24+nt
        int nt = tile % 24, kt = tile / 24;
        int k = kt * 32 + (lane >> 4) * 8 + j;
        int n = nt * 16 + (lane & 15);
        W2p[t] = (short)f2bf(W2[k * 384 + n]);
        return;
    }
    t -= W2P_ELEMS;
    if (t < WRP_ELEMS) {
        int j = t & 7, lane = (t >> 3) & 63, nt = t >> 9; // 0..23
        int k = (lane >> 4) * 8 + j;
        int n = nt * 16 + (lane & 15);
        float v = (k < NRBF) ? Wr[k * 384 + n] : 0.0f;
        Wrp[t] = (short)f2bf(v);
    }
}

// ---------------- counting sort by segment ----------------
__global__ void hist_kernel(const int* __restrict__ mapping,
                            int* __restrict__ counts, int E) {
    int t = blockIdx.x * blockDim.x + threadIdx.x;
    if (t < E) atomicAdd(&counts[mapping[t]], 1);
}

// one block of 64 threads; 64*32 = 2048 >= NCG
__global__ void scan_kernel(const int* __restrict__ counts,
                            int* __restrict__ start,
                            int* __restrict__ cursor) {
    int lane = threadIdx.x;          // 0..63
    int base = lane * 32;
    int loc[32];
    int s = 0;
#pragma unroll
    for (int j = 0; j < 32; ++j) {
        int idx = base + j;
        int c = (idx < NCG) ? counts[idx] : 0;
        loc[j] = s;
        s += c;
    }
    int inc = s;
#pragma unroll
    for (int off = 1; off < 64; off <<= 1) {
        int n = __shfl_up(inc, off, 64);
        if (lane >= off) inc += n;
    }
    int excl = inc - s;
#pragma unroll
    for (int j = 0; j < 32; ++j) {
        int idx = base + j;
        if (idx < NCG) {
            start[idx]  = excl + loc[j];
            cursor[idx] = excl + loc[j];
        }
    }
}

__global__ void scatter_kernel(const int* __restrict__ mapping,
                               int* __restrict__ cursor,
                               int* __restrict__ order, int E) {
    int t = blockIdx.x * blockDim.x + threadIdx.x;
    if (t < E) {
        int seg = mapping[t];
        int pos = atomicAdd(&cursor[seg], 1);
        order[pos] = t;
    }
}

// ---------------- main fused kernel: one block per segment ----------------
// R1's proven barrier-free schedule (wave w owns rows [16w,16w+16) of S/H
// tile, geometry buffers, accumulators; double-buffered geometry arrays;
// per-iteration: A(a1) B(prefetch ids) C(GEMM1) D(a2/rb/voff/v0) F(stage
// next tile into buffer p^1) E(ft ping-pong loop reading buffer p)) —
// minus R1's register pressure (R1 spilled at >128 VGPR): no persistent
// s_i staging registers (F does load+convert+write directly), and FTBODY
// re-reads env/unit from wave-private LDS instead of register arrays.
__global__ __launch_bounds__(256, 4) void
main_kernel(const float* __restrict__ s_i, const float* __restrict__ v_i,
            const float* __restrict__ r_iI, const float* __restrict__ b1,
            const float* __restrict__ b2, const float* __restrict__ br,
            const int* __restrict__ order, const int* __restrict__ start,
            const int* __restrict__ counts,
            const short* __restrict__ W1p, const short* __restrict__ W2p,
            const short* __restrict__ Wrp,
            float* __restrict__ out) {
    __shared__ __align__(16) short lds_sh[64 * LSTR];   // S tile, then H tile (wave-private rows)
    __shared__ float lds_acc[4 * 512];     // per-wave accumulators: [s:128][v:384]
    __shared__ float lds_bias[896];        // b2[0:384] br[384:768] b1[768:896]
    __shared__ int   lds_eid[2][64];       // double-buffered, wave-private rows
    __shared__ float lds_dist[2][64];
    __shared__ float lds_env[2][64];
    __shared__ float lds_unit[2][64][3];

    const int tid  = threadIdx.x;
    const int lane = tid & 63;
    const int w    = tid >> 6;       // wave 0..3
    const int lq   = lane >> 4;      // quad 0..3
    const int lc   = lane & 15;
    const int seg  = blockIdx.x;

    const int st  = start[seg];
    const int cnt = counts[seg];

    // staging assignment: 4 lanes per row, wave-private rows
    const int  R   = w * 16 + (lane >> 2);   // tile row this thread stages
    const int  sq  = lane & 3;               // quarter of the row
    const bool geo = (lane < 16);            // geometry lanes
    const int  G   = w * 16 + (lane & 15);   // geometry row (valid when geo)

    // zero per-wave accumulators + stage biases (only cross-wave init)
    for (int i = tid; i < 4 * 512; i += 256) lds_acc[i] = 0.0f;
    for (int i = tid; i < 896; i += 256)
        lds_bias[i] = (i < 384) ? b2[i] : (i < 768 ? br[i - 384] : b1[i - 768]);

    const bf16x8* W1f = reinterpret_cast<const bf16x8*>(W1p);
    const bf16x8* W2f = reinterpret_cast<const bf16x8*>(W2p);
    const bf16x8* Wrf = reinterpret_cast<const bf16x8*>(Wrp);

    __syncthreads();   // lds_acc + lds_bias visible; ONLY barrier before epilogue

    const int nT = (cnt + 63) >> 6;

    // ---- prologue: stage tile 0 (S rows + geometry buffer 0) ----
    if (nT > 0) {
        const int valid0 = min(64, cnt);
        {
            const int e0 = order[st + min(R, valid0 - 1)];
            const float4* src = reinterpret_cast<const float4*>(
                s_i + (size_t)e0 * FEATN + sq * 32);
            short* dst = lds_sh + R * LSTR + sq * 32;
#pragma unroll
            for (int c = 0; c < 8; ++c) {
                float4 v = src[c];
                unsigned int p0 = (unsigned int)f2bf(v.x) | ((unsigned int)f2bf(v.y) << 16);
                unsigned int p1 = (unsigned int)f2bf(v.z) | ((unsigned int)f2bf(v.w) << 16);
                *reinterpret_cast<uint2*>(dst + c * 4) = make_uint2(p0, p1);
            }
        }
        if (geo) {
            const int e0 = order[st + min(G, valid0 - 1)];
            float gx = r_iI[(size_t)e0 * 3 + 0];
            float gy = r_iI[(size_t)e0 * 3 + 1];
            float gz = r_iI[(size_t)e0 * 3 + 2];
            float d = sqrtf(gx * gx + gy * gy + gz * gz + 3e-8f);
            float inv_d = 1.0f / d;
            lds_dist[0][G] = d;
            lds_unit[0][G][0] = gx * inv_d;
            lds_unit[0][G][1] = gy * inv_d;
            lds_unit[0][G][2] = gz * inv_d;
            float env = (d < CUTF) ? 0.5f * (__cosf(PI_F * d / CUTF) + 1.0f) : 0.0f;
            lds_env[0][G] = (G < valid0) ? env : 0.0f;
            lds_eid[0][G] = e0;
        }
    }

    for (int t = 0; t < nT; ++t) {
        const int  p  = t & 1;
        const bool pf = (t + 1 < nT);

        // ---- A: GEMM1 A-fragments from current S tile ----
        bf16x8 a1[4];
#pragma unroll
        for (int kt = 0; kt < 4; ++kt)
            a1[kt] = *reinterpret_cast<const bf16x8*>(
                lds_sh + (w * 16 + lc) * LSTR + kt * 32 + lq * 8);

        // ---- B: issue next-tile id/geometry loads (consumed at F) ----
        int eR = 0, eG = 0, validn = 0;
        float gx = 0.f, gy = 0.f, gz = 0.f;
        if (pf) {
            validn = min(64, cnt - (t + 1) * 64);
            const int basen = st + (t + 1) * 64;
            eR = order[basen + min(R, validn - 1)];
            if (geo) {
                eG = order[basen + min(G, validn - 1)];
                gx = r_iI[(size_t)eG * 3 + 0];
                gy = r_iI[(size_t)eG * 3 + 1];
                gz = r_iI[(size_t)eG * 3 + 2];
            }
        }

        // ---- C: GEMM1: H = silu(S @ W1 + b1), written in-place (wave rows) ----
#pragma unroll
        for (int nt = 0; nt < 8; ++nt) {
            f32x4 acc = {0.f, 0.f, 0.f, 0.f};
#pragma unroll
            for (int kt = 0; kt < 4; ++kt)
                acc = __builtin_amdgcn_mfma_f32_16x16x32_bf16(
                    a1[kt], W1f[(kt * 8 + nt) * 64 + lane], acc, 0, 0, 0);
            float b1v = lds_bias[768 + nt * 16 + lc];
#pragma unroll
            for (int i = 0; i < 4; ++i) {
                float x = acc[i] + b1v;
                float h = x / (1.0f + __expf(-x));
                lds_sh[(w * 16 + lq * 4 + i) * LSTR + nt * 16 + lc] = (short)f2bf(h);
            }
        }

        // ---- D: GEMM2 A-fragments, rbf fragment, v offsets, first v load ----
        bf16x8 a2[4];
#pragma unroll
        for (int kt = 0; kt < 4; ++kt)
            a2[kt] = *reinterpret_cast<const bf16x8*>(
                lds_sh + (w * 16 + lc) * LSTR + kt * 32 + lq * 8);

        bf16x8 rb;
        {
            float d = lds_dist[p][w * 16 + lc];
            float inv_d = 1.0f / d;
            float x0 = PI_F * d / CUTF;
#pragma unroll
            for (int j = 0; j < 8; ++j) {
                int k = lq * 8 + j;
                float v = 0.0f;
                if (k < NRBF) v = __sinf((float)(k + 1) * x0) * inv_d;
                rb[j] = (short)f2bf(v);
            }
        }

        unsigned voff[4];
#pragma unroll
        for (int i = 0; i < 4; ++i)
            voff[i] = (unsigned)lds_eid[p][w * 16 + lq * 4 + i] * 1536u;

#define LOADV(VX, VY, VZ, ftv)                                               \
        if ((ftv) < 8) {                                                     \
            const int f_ = (ftv) * 16 + lc;                                  \
            _Pragma("unroll")                                                \
            for (int i_ = 0; i_ < 4; ++i_) {                                 \
                const float* vp_ = (const float*)((const char*)v_i +         \
                                                  voff[i_] + f_ * 12);       \
                VX[i_] = vp_[0]; VY[i_] = vp_[1]; VZ[i_] = vp_[2];           \
            }                                                                \
        }

        float vAx[4], vAy[4], vAz[4], vBx[4], vBy[4], vBz[4];
        LOADV(vAx, vAy, vAz, 0)          // flies during F's staging work

        // ---- F: stage next tile (S rows + geometry buffer p^1) ----
        if (pf) {
            {
                const float4* src = reinterpret_cast<const float4*>(
                    s_i + (size_t)eR * FEATN + sq * 32);
                short* dst = lds_sh + R * LSTR + sq * 32;
#pragma unroll
                for (int c = 0; c < 8; ++c) {
                    float4 v = src[c];
                    unsigned int p0 = (unsigned int)f2bf(v.x) | ((unsigned int)f2bf(v.y) << 16);
                    unsigned int p1 = (unsigned int)f2bf(v.z) | ((unsigned int)f2bf(v.w) << 16);
                    *reinterpret_cast<uint2*>(dst + c * 4) = make_uint2(p0, p1);
                }
            }
            if (geo) {
                const int pn = p ^ 1;
                float d = sqrtf(gx * gx + gy * gy + gz * gz + 3e-8f);
                float inv_d = 1.0f / d;
                lds_dist[pn][G] = d;
                lds_unit[pn][G][0] = gx * inv_d;
                lds_unit[pn][G][1] = gy * inv_d;
                lds_unit[pn][G][2] = gz * inv_d;
                float env = (d < CUTF) ? 0.5f * (__cosf(PI_F * d / CUTF) + 1.0f) : 0.0f;
                lds_env[pn][G] = (G < validn) ? env : 0.0f;
                lds_eid[pn][G] = eG;
            }
        }

        // ---- E: GEMM2 + RBF + epilogue, v_i ping-pong prefetch ----
        float* aw = lds_acc + w * 512;

#define FTBODY(ftv, VX, VY, VZ) {                                            \
            const int ft_ = (ftv);                                           \
            f32x4 acc0 = {0.f,0.f,0.f,0.f}, acc1 = {0.f,0.f,0.f,0.f},        \
                  acc2 = {0.f,0.f,0.f,0.f};                                  \
            __builtin_amdgcn_s_setprio(1);                                   \
            _Pragma("unroll")                                                \
            for (int kt_ = 0; kt_ < 4; ++kt_) {                              \
                bf16x8 a_ = a2[kt_];                                         \
                acc0 = __builtin_amdgcn_mfma_f32_16x16x32_bf16(              \
                    a_, W2f[(kt_ * 24 + ft_     ) * 64 + lane], acc0, 0,0,0);\
                acc1 = __builtin_amdgcn_mfma_f32_16x16x32_bf16(              \
                    a_, W2f[(kt_ * 24 + ft_ +  8) * 64 + lane], acc1, 0,0,0);\
                acc2 = __builtin_amdgcn_mfma_f32_16x16x32_bf16(              \
                    a_, W2f[(kt_ * 24 + ft_ + 16) * 64 + lane], acc2, 0,0,0);\
            }                                                                \
            f32x4 z4 = {0.f,0.f,0.f,0.f};                                    \
            f32x4 wa0 = __builtin_amdgcn_mfma_f32_16x16x32_bf16(             \
                rb, Wrf[(ft_     ) * 64 + lane], z4, 0, 0, 0);               \
            f32x4 wa1 = __builtin_amdgcn_mfma_f32_16x16x32_bf16(             \
                rb, Wrf[(ft_ +  8) * 64 + lane], z4, 0, 0, 0);               \
            f32x4 wa2 = __builtin_amdgcn_mfma_f32_16x16x32_bf16(             \
                rb, Wrf[(ft_ + 16) * 64 + lane], z4, 0, 0, 0);               \
            __builtin_amdgcn_s_setprio(0);                                   \
            const int f_ = ft_ * 16 + lc;                                    \
            float b2v0 = lds_bias[f_], b2v1 = lds_bias[128 + f_],            \
                  b2v2 = lds_bias[256 + f_];                                 \
            float brv0 = lds_bias[384 + f_], brv1 = lds_bias[512 + f_],      \
                  brv2 = lds_bias[640 + f_];                                 \
            float sds = 0.f, svx = 0.f, svy = 0.f, svz = 0.f;                \
            _Pragma("unroll")                                                \
            for (int i_ = 0; i_ < 4; ++i_) {                                 \
                const int e_ = w * 16 + lq * 4 + i_;                         \
                const float env_ = lds_env[p][e_];                           \
                float phi0 = acc0[i_] + b2v0;                                \
                float phi1 = acc1[i_] + b2v1;                                \
                float phi2 = acc2[i_] + b2v2;                                \
                float w0 = (wa0[i_] + brv0) * env_;                          \
                float w1 = (wa1[i_] + brv1) * env_;                          \
                float w2 = (wa2[i_] + brv2) * env_;                          \
                float inv0 = phi0 * w0;                                      \
                float inv1 = phi1 * w1;                                      \
                float inv2 = phi2 * w2;                                      \
                sds += inv1;                                                 \
                svx += inv2 * lds_unit[p][e_][0] + inv0 * VX[i_];            \
                svy += inv2 * lds_unit[p][e_][1] + inv0 * VY[i_];            \
                svz += inv2 * lds_unit[p][e_][2] + inv0 * VZ[i_];            \
            }                                                                \
            sds += __shfl_xor(sds, 16); sds += __shfl_xor(sds, 32);          \
            svx += __shfl_xor(svx, 16); svx += __shfl_xor(svx, 32);          \
            svy += __shfl_xor(svy, 16); svy += __shfl_xor(svy, 32);          \
            svz += __shfl_xor(svz, 16); svz += __shfl_xor(svz, 32);          \
            if (lq == 0) {                                                   \
                aw[f_]               += sds;                                 \
                aw[128 + f_ * 3 + 0] += svx;                                 \
                aw[128 + f_ * 3 + 1] += svy;                                 \
                aw[128 + f_ * 3 + 2] += svz;                                 \
            }                                                                \
        }

#pragma unroll 1
        for (int fp = 0; fp < 4; ++fp) {
            const int ft0 = fp * 2;
            LOADV(vBx, vBy, vBz, ft0 + 1)
            FTBODY(ft0, vAx, vAy, vAz)
            LOADV(vAx, vAy, vAz, ft0 + 2)
            FTBODY(ft0 + 1, vBx, vBy, vBz)
        }
#undef LOADV
#undef FTBODY
    }
    __syncthreads();

    // ---- final: cross-wave reduce, mean, write out ----
    const float invc = (cnt > 0) ? (1.0f / (float)cnt) : 0.0f;
    const int NS = NCG * 128;
    for (int o = tid; o < 512; o += 256) {
        float v = lds_acc[o] + lds_acc[512 + o] + lds_acc[1024 + o] + lds_acc[1536 + o];
        v *= invc;
        if (o < 128) out[(size_t)seg * 128 + o] = v;
        else         out[NS + (size_t)seg * 384 + (o - 128)] = v;
    }
}

extern "C" void kernel_launch(void* const* d_in, const int* in_sizes, int n_in,
                              void* d_out, int out_size, void* d_ws, size_t ws_size,
                              hipStream_t stream) {
    const float* s_i  = (const float*)d_in[0];
    const float* v_i  = (const float*)d_in[1];
    const float* r_iI = (const float*)d_in[2];
    const float* W1   = (const float*)d_in[3];
    const float* b1   = (const float*)d_in[4];
    const float* W2   = (const float*)d_in[5];
    const float* b2   = (const float*)d_in[6];
    const float* Wr   = (const float*)d_in[7];
    const float* br   = (const float*)d_in[8];
    const int* mapping = (const int*)d_in[9];
    // d_in[10] = num_cg (compile-time NCG=2000)

    const int E = in_sizes[0] / FEATN;   // 200000

    char* ws = (char*)d_ws;
    int*   counts = (int*)(ws + 0);          //  8,000 B
    int*   start  = (int*)(ws + 8192);       //  8,000 B
    int*   cursor = (int*)(ws + 16384);      //  8,000 B
    int*   order  = (int*)(ws + 24576);      // 800,000 B
    short* W1p    = (short*)(ws + 829440);   // 32,768 B
    short* W2p    = (short*)(ws + 862208);   // 98,304 B
    short* Wrp    = (short*)(ws + 960512);   // 24,576 B

    hipMemsetAsync(counts, 0, NCG * sizeof(int), stream);
    pack_weights<<<(W1P_ELEMS + W2P_ELEMS + WRP_ELEMS) / 256, 256, 0, stream>>>(
        W1, W2, Wr, W1p, W2p, Wrp);
    hist_kernel<<<(E + 255) / 256, 256, 0, stream>>>(mapping, counts, E);
    scan_kernel<<<1, 64, 0, stream>>>(counts, start, cursor);
    scatter_kernel<<<(E + 255) / 256, 256, 0, stream>>>(mapping, cursor, order, E);
    main_kernel<<<NCG, 256, 0, stream>>>(s_i, v_i, r_iI, b1, b2, br,
                                         order, start, counts,
                                         W1p, W2p, Wrp, (float*)d_out);
}

// Round 5
// 794.662 us; speedup vs baseline: 1.3344x; 1.1878x over previous
//
#include <hip/hip_runtime.h>
#include <math.h>

// Problem constants (fixed by setup_inputs)
#define FEATN 128
#define NRBF  20
#define NCG   2000
#define CUTF  5.0f
#define PI_F  3.14159265358979323846f

// LDS row stride in bf16 units: 128 + 8 pad (16B-aligned, breaks bank conflicts)
#define LSTR 136

typedef __attribute__((ext_vector_type(8))) short bf16x8;
typedef __attribute__((ext_vector_type(4))) float f32x4;

__device__ inline unsigned short f2bf(float x) {
    unsigned int u = __float_as_uint(x);
    u += 0x7fffu + ((u >> 16) & 1u);
    return (unsigned short)(u >> 16);
}

// ---------------- weight packing ----------------
// B-fragment layout for mfma_f32_16x16x32_bf16:
//   lane holds B[k][n] with n = nt*16 + (lane&15), k = kt*32 + (lane>>4)*8 + j, j=0..7
// packed flat: (((kt*NT + nt)*64 + lane)*8 + j)
#define W1P_ELEMS (4*8*64*8)    // 16384
#define W2P_ELEMS (4*24*64*8)   // 49152
#define WRP_ELEMS (24*64*8)     // 12288  (K padded 20->32, single kt)

__global__ void pack_weights(const float* __restrict__ W1,
                             const float* __restrict__ W2,
                             const float* __restrict__ Wr,
                             short* __restrict__ W1p,
                             short* __restrict__ W2p,
                             short* __restrict__ Wrp) {
    int t = blockIdx.x * blockDim.x + threadIdx.x;
    if (t < W1P_ELEMS) {
        int j = t & 7, lane = (t >> 3) & 63, tile = t >> 9; // tile = kt*8+nt
        int nt = tile & 7, kt = tile >> 3;
        int k = kt * 32 + (lane >> 4) * 8 + j;
        int n = nt * 16 + (lane & 15);
        W1p[t] = (short)f2bf(W1[k * 128 + n]);
        return;
    }
    t -= W1P_ELEMS;
    if (t < W2P_ELEMS) {
        int j = t & 7, lane = (t >> 3) & 63, tile = t >> 9; // tile = kt*24+nt
        int nt = tile % 24, kt = tile / 24;
        int k = kt * 32 + (lane >> 4) * 8 + j;
        int n = nt * 16 + (lane & 15);
        W2p[t] = (short)f2bf(W2[k * 384 + n]);
        return;
    }
    t -= W2P_ELEMS;
    if (t < WRP_ELEMS) {
        int j = t & 7, lane = (t >> 3) & 63, nt = t >> 9; // 0..23
        int k = (lane >> 4) * 8 + j;
        int n = nt * 16 + (lane & 15);
        float v = (k < NRBF) ? Wr[k * 384 + n] : 0.0f;
        Wrp[t] = (short)f2bf(v);
    }
}

// ---------------- counting sort by segment ----------------
__global__ void hist_kernel(const int* __restrict__ mapping,
                            int* __restrict__ counts, int E) {
    int t = blockIdx.x * blockDim.x + threadIdx.x;
    if (t < E) atomicAdd(&counts[mapping[t]], 1);
}

// one block of 64 threads; 64*32 = 2048 >= NCG
__global__ void scan_kernel(const int* __restrict__ counts,
                            int* __restrict__ start,
                            int* __restrict__ cursor) {
    int lane = threadIdx.x;          // 0..63
    int base = lane * 32;
    int loc[32];
    int s = 0;
#pragma unroll
    for (int j = 0; j < 32; ++j) {
        int idx = base + j;
        int c = (idx < NCG) ? counts[idx] : 0;
        loc[j] = s;
        s += c;
    }
    int inc = s;
#pragma unroll
    for (int off = 1; off < 64; off <<= 1) {
        int n = __shfl_up(inc, off, 64);
        if (lane >= off) inc += n;
    }
    int excl = inc - s;
#pragma unroll
    for (int j = 0; j < 32; ++j) {
        int idx = base + j;
        if (idx < NCG) {
            start[idx]  = excl + loc[j];
            cursor[idx] = excl + loc[j];
        }
    }
}

__global__ void scatter_kernel(const int* __restrict__ mapping,
                               int* __restrict__ cursor,
                               int* __restrict__ order, int E) {
    int t = blockIdx.x * blockDim.x + threadIdx.x;
    if (t < E) {
        int seg = mapping[t];
        int pos = atomicAdd(&cursor[seg], 1);
        order[pos] = t;
    }
}

// ---------------- main fused kernel: one block per segment ----------------
// Barrier-free wave-private schedule (wave w owns rows [16w,16w+16) of S/H
// tile, geometry buffers, accumulators; double-buffered geometry arrays;
// per-iteration: A(a1) B(prefetch ids) C(GEMM1) D(a2/rb/voff/v0) F(stage
// next tile into buffer p^1) E(ft ping-pong loop reading buffer p)).
// launch_bounds(256,3): per-SIMD VGPR pool 512 / 3 waves = 170-reg cap.
// R1/R4 post-mortem: (256,4)'s 128-reg cap forced scratch spill (TCC
// WRITE_SIZE 566-760 MB vs ~4 MB real output). E-phase peak pressure is
// ~160-170 live VGPRs; 3 waves/EU keeps occupancy ~12 waves/CU (~measured
// 13 before) while eliminating the spill round-trip.
__global__ __launch_bounds__(256, 3) void
main_kernel(const float* __restrict__ s_i, const float* __restrict__ v_i,
            const float* __restrict__ r_iI, const float* __restrict__ b1,
            const float* __restrict__ b2, const float* __restrict__ br,
            const int* __restrict__ order, const int* __restrict__ start,
            const int* __restrict__ counts,
            const short* __restrict__ W1p, const short* __restrict__ W2p,
            const short* __restrict__ Wrp,
            float* __restrict__ out) {
    __shared__ __align__(16) short lds_sh[64 * LSTR];   // S tile, then H tile (wave-private rows)
    __shared__ float lds_acc[4 * 512];     // per-wave accumulators: [s:128][v:384]
    __shared__ float lds_bias[896];        // b2[0:384] br[384:768] b1[768:896]
    __shared__ int   lds_eid[2][64];       // double-buffered, wave-private rows
    __shared__ float lds_dist[2][64];
    __shared__ float lds_env[2][64];
    __shared__ float lds_unit[2][64][3];

    const int tid  = threadIdx.x;
    const int lane = tid & 63;
    const int w    = tid >> 6;       // wave 0..3
    const int lq   = lane >> 4;      // quad 0..3
    const int lc   = lane & 15;
    const int seg  = blockIdx.x;

    const int st  = start[seg];
    const int cnt = counts[seg];

    // staging assignment: 4 lanes per row, wave-private rows
    const int  R   = w * 16 + (lane >> 2);   // tile row this thread stages
    const int  sq  = lane & 3;               // quarter of the row
    const bool geo = (lane < 16);            // geometry lanes
    const int  G   = w * 16 + (lane & 15);   // geometry row (valid when geo)

    // zero per-wave accumulators + stage biases (only cross-wave init)
    for (int i = tid; i < 4 * 512; i += 256) lds_acc[i] = 0.0f;
    for (int i = tid; i < 896; i += 256)
        lds_bias[i] = (i < 384) ? b2[i] : (i < 768 ? br[i - 384] : b1[i - 768]);

    const bf16x8* W1f = reinterpret_cast<const bf16x8*>(W1p);
    const bf16x8* W2f = reinterpret_cast<const bf16x8*>(W2p);
    const bf16x8* Wrf = reinterpret_cast<const bf16x8*>(Wrp);

    __syncthreads();   // lds_acc + lds_bias visible; ONLY barrier before epilogue

    const int nT = (cnt + 63) >> 6;

    // ---- prologue: stage tile 0 (S rows + geometry buffer 0) ----
    if (nT > 0) {
        const int valid0 = min(64, cnt);
        {
            const int e0 = order[st + min(R, valid0 - 1)];
            const float4* src = reinterpret_cast<const float4*>(
                s_i + (size_t)e0 * FEATN + sq * 32);
            short* dst = lds_sh + R * LSTR + sq * 32;
#pragma unroll
            for (int c = 0; c < 8; ++c) {
                float4 v = src[c];
                unsigned int p0 = (unsigned int)f2bf(v.x) | ((unsigned int)f2bf(v.y) << 16);
                unsigned int p1 = (unsigned int)f2bf(v.z) | ((unsigned int)f2bf(v.w) << 16);
                *reinterpret_cast<uint2*>(dst + c * 4) = make_uint2(p0, p1);
            }
        }
        if (geo) {
            const int e0 = order[st + min(G, valid0 - 1)];
            float gx = r_iI[(size_t)e0 * 3 + 0];
            float gy = r_iI[(size_t)e0 * 3 + 1];
            float gz = r_iI[(size_t)e0 * 3 + 2];
            float d = sqrtf(gx * gx + gy * gy + gz * gz + 3e-8f);
            float inv_d = 1.0f / d;
            lds_dist[0][G] = d;
            lds_unit[0][G][0] = gx * inv_d;
            lds_unit[0][G][1] = gy * inv_d;
            lds_unit[0][G][2] = gz * inv_d;
            float env = (d < CUTF) ? 0.5f * (__cosf(PI_F * d / CUTF) + 1.0f) : 0.0f;
            lds_env[0][G] = (G < valid0) ? env : 0.0f;
            lds_eid[0][G] = e0;
        }
    }

    for (int t = 0; t < nT; ++t) {
        const int  p  = t & 1;
        const bool pf = (t + 1 < nT);

        // ---- A: GEMM1 A-fragments from current S tile ----
        bf16x8 a1[4];
#pragma unroll
        for (int kt = 0; kt < 4; ++kt)
            a1[kt] = *reinterpret_cast<const bf16x8*>(
                lds_sh + (w * 16 + lc) * LSTR + kt * 32 + lq * 8);

        // ---- B: issue next-tile id/geometry loads (consumed at F) ----
        int eR = 0, eG = 0, validn = 0;
        float gx = 0.f, gy = 0.f, gz = 0.f;
        if (pf) {
            validn = min(64, cnt - (t + 1) * 64);
            const int basen = st + (t + 1) * 64;
            eR = order[basen + min(R, validn - 1)];
            if (geo) {
                eG = order[basen + min(G, validn - 1)];
                gx = r_iI[(size_t)eG * 3 + 0];
                gy = r_iI[(size_t)eG * 3 + 1];
                gz = r_iI[(size_t)eG * 3 + 2];
            }
        }

        // ---- C: GEMM1: H = silu(S @ W1 + b1), written in-place (wave rows) ----
#pragma unroll
        for (int nt = 0; nt < 8; ++nt) {
            f32x4 acc = {0.f, 0.f, 0.f, 0.f};
#pragma unroll
            for (int kt = 0; kt < 4; ++kt)
                acc = __builtin_amdgcn_mfma_f32_16x16x32_bf16(
                    a1[kt], W1f[(kt * 8 + nt) * 64 + lane], acc, 0, 0, 0);
            float b1v = lds_bias[768 + nt * 16 + lc];
#pragma unroll
            for (int i = 0; i < 4; ++i) {
                float x = acc[i] + b1v;
                float h = x / (1.0f + __expf(-x));
                lds_sh[(w * 16 + lq * 4 + i) * LSTR + nt * 16 + lc] = (short)f2bf(h);
            }
        }

        // ---- D: GEMM2 A-fragments, rbf fragment, v offsets, first v load ----
        bf16x8 a2[4];
#pragma unroll
        for (int kt = 0; kt < 4; ++kt)
            a2[kt] = *reinterpret_cast<const bf16x8*>(
                lds_sh + (w * 16 + lc) * LSTR + kt * 32 + lq * 8);

        bf16x8 rb;
        {
            float d = lds_dist[p][w * 16 + lc];
            float inv_d = 1.0f / d;
            float x0 = PI_F * d / CUTF;
#pragma unroll
            for (int j = 0; j < 8; ++j) {
                int k = lq * 8 + j;
                float v = 0.0f;
                if (k < NRBF) v = __sinf((float)(k + 1) * x0) * inv_d;
                rb[j] = (short)f2bf(v);
            }
        }

        unsigned voff[4];
#pragma unroll
        for (int i = 0; i < 4; ++i)
            voff[i] = (unsigned)lds_eid[p][w * 16 + lq * 4 + i] * 1536u;

#define LOADV(VX, VY, VZ, ftv)                                               \
        if ((ftv) < 8) {                                                     \
            const int f_ = (ftv) * 16 + lc;                                  \
            _Pragma("unroll")                                                \
            for (int i_ = 0; i_ < 4; ++i_) {                                 \
                const float* vp_ = (const float*)((const char*)v_i +         \
                                                  voff[i_] + f_ * 12);       \
                VX[i_] = vp_[0]; VY[i_] = vp_[1]; VZ[i_] = vp_[2];           \
            }                                                                \
        }

        float vAx[4], vAy[4], vAz[4], vBx[4], vBy[4], vBz[4];
        LOADV(vAx, vAy, vAz, 0)          // flies during F's staging work

        // ---- F: stage next tile (S rows + geometry buffer p^1) ----
        if (pf) {
            {
                const float4* src = reinterpret_cast<const float4*>(
                    s_i + (size_t)eR * FEATN + sq * 32);
                short* dst = lds_sh + R * LSTR + sq * 32;
#pragma unroll
                for (int c = 0; c < 8; ++c) {
                    float4 v = src[c];
                    unsigned int p0 = (unsigned int)f2bf(v.x) | ((unsigned int)f2bf(v.y) << 16);
                    unsigned int p1 = (unsigned int)f2bf(v.z) | ((unsigned int)f2bf(v.w) << 16);
                    *reinterpret_cast<uint2*>(dst + c * 4) = make_uint2(p0, p1);
                }
            }
            if (geo) {
                const int pn = p ^ 1;
                float d = sqrtf(gx * gx + gy * gy + gz * gz + 3e-8f);
                float inv_d = 1.0f / d;
                lds_dist[pn][G] = d;
                lds_unit[pn][G][0] = gx * inv_d;
                lds_unit[pn][G][1] = gy * inv_d;
                lds_unit[pn][G][2] = gz * inv_d;
                float env = (d < CUTF) ? 0.5f * (__cosf(PI_F * d / CUTF) + 1.0f) : 0.0f;
                lds_env[pn][G] = (G < validn) ? env : 0.0f;
                lds_eid[pn][G] = eG;
            }
        }

        // ---- E: GEMM2 + RBF + epilogue, v_i ping-pong prefetch ----
        float* aw = lds_acc + w * 512;

#define FTBODY(ftv, VX, VY, VZ) {                                            \
            const int ft_ = (ftv);                                           \
            f32x4 acc0 = {0.f,0.f,0.f,0.f}, acc1 = {0.f,0.f,0.f,0.f},        \
                  acc2 = {0.f,0.f,0.f,0.f};                                  \
            __builtin_amdgcn_s_setprio(1);                                   \
            _Pragma("unroll")                                                \
            for (int kt_ = 0; kt_ < 4; ++kt_) {                              \
                bf16x8 a_ = a2[kt_];                                         \
                acc0 = __builtin_amdgcn_mfma_f32_16x16x32_bf16(              \
                    a_, W2f[(kt_ * 24 + ft_     ) * 64 + lane], acc0, 0,0,0);\
                acc1 = __builtin_amdgcn_mfma_f32_16x16x32_bf16(              \
                    a_, W2f[(kt_ * 24 + ft_ +  8) * 64 + lane], acc1, 0,0,0);\
                acc2 = __builtin_amdgcn_mfma_f32_16x16x32_bf16(              \
                    a_, W2f[(kt_ * 24 + ft_ + 16) * 64 + lane], acc2, 0,0,0);\
            }                                                                \
            f32x4 z4 = {0.f,0.f,0.f,0.f};                                    \
            f32x4 wa0 = __builtin_amdgcn_mfma_f32_16x16x32_bf16(             \
                rb, Wrf[(ft_     ) * 64 + lane], z4, 0, 0, 0);               \
            f32x4 wa1 = __builtin_amdgcn_mfma_f32_16x16x32_bf16(             \
                rb, Wrf[(ft_ +  8) * 64 + lane], z4, 0, 0, 0);               \
            f32x4 wa2 = __builtin_amdgcn_mfma_f32_16x16x32_bf16(             \
                rb, Wrf[(ft_ + 16) * 64 + lane], z4, 0, 0, 0);               \
            __builtin_amdgcn_s_setprio(0);                                   \
            const int f_ = ft_ * 16 + lc;                                    \
            float b2v0 = lds_bias[f_], b2v1 = lds_bias[128 + f_],            \
                  b2v2 = lds_bias[256 + f_];                                 \
            float brv0 = lds_bias[384 + f_], brv1 = lds_bias[512 + f_],      \
                  brv2 = lds_bias[640 + f_];                                 \
            float sds = 0.f, svx = 0.f, svy = 0.f, svz = 0.f;                \
            _Pragma("unroll")                                                \
            for (int i_ = 0; i_ < 4; ++i_) {                                 \
                const int e_ = w * 16 + lq * 4 + i_;                         \
                const float env_ = lds_env[p][e_];                           \
                float phi0 = acc0[i_] + b2v0;                                \
                float phi1 = acc1[i_] + b2v1;                                \
                float phi2 = acc2[i_] + b2v2;                                \
                float w0 = (wa0[i_] + brv0) * env_;                          \
                float w1 = (wa1[i_] + brv1) * env_;                          \
                float w2 = (wa2[i_] + brv2) * env_;                          \
                float inv0 = phi0 * w0;                                      \
                float inv1 = phi1 * w1;                                      \
                float inv2 = phi2 * w2;                                      \
                sds += inv1;                                                 \
                svx += inv2 * lds_unit[p][e_][0] + inv0 * VX[i_];            \
                svy += inv2 * lds_unit[p][e_][1] + inv0 * VY[i_];            \
                svz += inv2 * lds_unit[p][e_][2] + inv0 * VZ[i_];            \
            }                                                                \
            sds += __shfl_xor(sds, 16); sds += __shfl_xor(sds, 32);          \
            svx += __shfl_xor(svx, 16); svx += __shfl_xor(svx, 32);          \
            svy += __shfl_xor(svy, 16); svy += __shfl_xor(svy, 32);          \
            svz += __shfl_xor(svz, 16); svz += __shfl_xor(svz, 32);          \
            if (lq == 0) {                                                   \
                aw[f_]               += sds;                                 \
                aw[128 + f_ * 3 + 0] += svx;                                 \
                aw[128 + f_ * 3 + 1] += svy;                                 \
                aw[128 + f_ * 3 + 2] += svz;                                 \
            }                                                                \
        }

#pragma unroll 1
        for (int fp = 0; fp < 4; ++fp) {
            const int ft0 = fp * 2;
            LOADV(vBx, vBy, vBz, ft0 + 1)
            FTBODY(ft0, vAx, vAy, vAz)
            LOADV(vAx, vAy, vAz, ft0 + 2)
            FTBODY(ft0 + 1, vBx, vBy, vBz)
        }
#undef LOADV
#undef FTBODY
    }
    __syncthreads();

    // ---- final: cross-wave reduce, mean, write out ----
    const float invc = (cnt > 0) ? (1.0f / (float)cnt) : 0.0f;
    const int NS = NCG * 128;
    for (int o = tid; o < 512; o += 256) {
        float v = lds_acc[o] + lds_acc[512 + o] + lds_acc[1024 + o] + lds_acc[1536 + o];
        v *= invc;
        if (o < 128) out[(size_t)seg * 128 + o] = v;
        else         out[NS + (size_t)seg * 384 + (o - 128)] = v;
    }
}

extern "C" void kernel_launch(void* const* d_in, const int* in_sizes, int n_in,
                              void* d_out, int out_size, void* d_ws, size_t ws_size,
                              hipStream_t stream) {
    const float* s_i  = (const float*)d_in[0];
    const float* v_i  = (const float*)d_in[1];
    const float* r_iI = (const float*)d_in[2];
    const float* W1   = (const float*)d_in[3];
    const float* b1   = (const float*)d_in[4];
    const float* W2   = (const float*)d_in[5];
    const float* b2   = (const float*)d_in[6];
    const float* Wr   = (const float*)d_in[7];
    const float* br   = (const float*)d_in[8];
    const int* mapping = (const int*)d_in[9];
    // d_in[10] = num_cg (compile-time NCG=2000)

    const int E = in_sizes[0] / FEATN;   // 200000

    char* ws = (char*)d_ws;
    int*   counts = (int*)(ws + 0);          //  8,000 B
    int*   start  = (int*)(ws + 8192);       //  8,000 B
    int*   cursor = (int*)(ws + 16384);      //  8,000 B
    int*   order  = (int*)(ws + 24576);      // 800,000 B
    short* W1p    = (short*)(ws + 829440);   // 32,768 B
    short* W2p    = (short*)(ws + 862208);   // 98,304 B
    short* Wrp    = (short*)(ws + 960512);   // 24,576 B

    hipMemsetAsync(counts, 0, NCG * sizeof(int), stream);
    pack_weights<<<(W1P_ELEMS + W2P_ELEMS + WRP_ELEMS) / 256, 256, 0, stream>>>(
        W1, W2, Wr, W1p, W2p, Wrp);
    hist_kernel<<<(E + 255) / 256, 256, 0, stream>>>(mapping, counts, E);
    scan_kernel<<<1, 64, 0, stream>>>(counts, start, cursor);
    scatter_kernel<<<(E + 255) / 256, 256, 0, stream>>>(mapping, cursor, order, E);
    main_kernel<<<NCG, 256, 0, stream>>>(s_i, v_i, r_iI, b1, b2, br,
                                         order, start, counts,
                                         W1p, W2p, Wrp, (float*)d_out);
}

// Round 6
// 765.760 us; speedup vs baseline: 1.3848x; 1.0377x over previous
//
#include <hip/hip_runtime.h>
#include <math.h>

// Problem constants (fixed by setup_inputs)
#define FEATN 128
#define NRBF  20
#define NCG   2000
#define CUTF  5.0f
#define PI_F  3.14159265358979323846f

// LDS row stride in bf16 units: 128 + 8 pad (16B-aligned, breaks bank conflicts)
#define LSTR 136

typedef __attribute__((ext_vector_type(8))) short bf16x8;
typedef __attribute__((ext_vector_type(4))) float f32x4;

__device__ inline unsigned short f2bf(float x) {
    unsigned int u = __float_as_uint(x);
    u += 0x7fffu + ((u >> 16) & 1u);
    return (unsigned short)(u >> 16);
}

// ---------------- weight packing ----------------
// B-fragment layout for mfma_f32_16x16x32_bf16:
//   lane holds B[k][n] with n = nt*16 + (lane&15), k = kt*32 + (lane>>4)*8 + j, j=0..7
// packed flat: (((kt*NT + nt)*64 + lane)*8 + j)
#define W1P_ELEMS (4*8*64*8)    // 16384
#define W2P_ELEMS (4*24*64*8)   // 49152
#define WRP_ELEMS (24*64*8)     // 12288  (K padded 20->32, single kt)

__global__ void pack_weights(const float* __restrict__ W1,
                             const float* __restrict__ W2,
                             const float* __restrict__ Wr,
                             short* __restrict__ W1p,
                             short* __restrict__ W2p,
                             short* __restrict__ Wrp) {
    int t = blockIdx.x * blockDim.x + threadIdx.x;
    if (t < W1P_ELEMS) {
        int j = t & 7, lane = (t >> 3) & 63, tile = t >> 9; // tile = kt*8+nt
        int nt = tile & 7, kt = tile >> 3;
        int k = kt * 32 + (lane >> 4) * 8 + j;
        int n = nt * 16 + (lane & 15);
        W1p[t] = (short)f2bf(W1[k * 128 + n]);
        return;
    }
    t -= W1P_ELEMS;
    if (t < W2P_ELEMS) {
        int j = t & 7, lane = (t >> 3) & 63, tile = t >> 9; // tile = kt*24+nt
        int nt = tile % 24, kt = tile / 24;
        int k = kt * 32 + (lane >> 4) * 8 + j;
        int n = nt * 16 + (lane & 15);
        W2p[t] = (short)f2bf(W2[k * 384 + n]);
        return;
    }
    t -= W2P_ELEMS;
    if (t < WRP_ELEMS) {
        int j = t & 7, lane = (t >> 3) & 63, nt = t >> 9; // 0..23
        int k = (lane >> 4) * 8 + j;
        int n = nt * 16 + (lane & 15);
        float v = (k < NRBF) ? Wr[k * 384 + n] : 0.0f;
        Wrp[t] = (short)f2bf(v);
    }
}

// ---------------- counting sort by segment ----------------
__global__ void hist_kernel(const int* __restrict__ mapping,
                            int* __restrict__ counts, int E) {
    int t = blockIdx.x * blockDim.x + threadIdx.x;
    if (t < E) atomicAdd(&counts[mapping[t]], 1);
}

// one block of 64 threads; 64*32 = 2048 >= NCG
__global__ void scan_kernel(const int* __restrict__ counts,
                            int* __restrict__ start,
                            int* __restrict__ cursor) {
    int lane = threadIdx.x;          // 0..63
    int base = lane * 32;
    int loc[32];
    int s = 0;
#pragma unroll
    for (int j = 0; j < 32; ++j) {
        int idx = base + j;
        int c = (idx < NCG) ? counts[idx] : 0;
        loc[j] = s;
        s += c;
    }
    int inc = s;
#pragma unroll
    for (int off = 1; off < 64; off <<= 1) {
        int n = __shfl_up(inc, off, 64);
        if (lane >= off) inc += n;
    }
    int excl = inc - s;
#pragma unroll
    for (int j = 0; j < 32; ++j) {
        int idx = base + j;
        if (idx < NCG) {
            start[idx]  = excl + loc[j];
            cursor[idx] = excl + loc[j];
        }
    }
}

__global__ void scatter_kernel(const int* __restrict__ mapping,
                               int* __restrict__ cursor,
                               int* __restrict__ order, int E) {
    int t = blockIdx.x * blockDim.x + threadIdx.x;
    if (t < E) {
        int seg = mapping[t];
        int pos = atomicAdd(&cursor[seg], 1);
        order[pos] = t;
    }
}

// ---------------- main fused kernel: one block per segment ----------------
// Barrier-free wave-private schedule (wave w owns rows [16w,16w+16) of S/H
// tile, geometry buffers, accumulators; double-buffered geometry arrays;
// per-iteration: A(a1) B(prefetch ids) C(GEMM1) D(a2/rb/voff/v0) F(stage
// next tile into buffer p^1) E(ft ping-pong loop reading buffer p)).
//
// launch_bounds dose-response (measured): (256,4) -> allocator picks 64-VGPR
// tier, WRITE_SIZE 566 MB scratch spill, main 550us. (256,3) -> 84-VGPR
// tier, WRITE 290 MB, main 385us. Real output is 4 MB; allocator is
// tier-targeting above the requested occupancy and paying in scratch.
// (256,2): cap 256 -> next tier ~128-170 VGPR fits E-phase peak live state
// (~130-150 regs) without spill. Occupancy floor 8 waves/CU; waves are
// independent pipelines, spill-removal has beaten occupancy each round.
__global__ __launch_bounds__(256, 2) void
main_kernel(const float* __restrict__ s_i, const float* __restrict__ v_i,
            const float* __restrict__ r_iI, const float* __restrict__ b1,
            const float* __restrict__ b2, const float* __restrict__ br,
            const int* __restrict__ order, const int* __restrict__ start,
            const int* __restrict__ counts,
            const short* __restrict__ W1p, const short* __restrict__ W2p,
            const short* __restrict__ Wrp,
            float* __restrict__ out) {
    __shared__ __align__(16) short lds_sh[64 * LSTR];   // S tile, then H tile (wave-private rows)
    __shared__ float lds_acc[4 * 512];     // per-wave accumulators: [s:128][v:384]
    __shared__ float lds_bias[896];        // b2[0:384] br[384:768] b1[768:896]
    __shared__ int   lds_eid[2][64];       // double-buffered, wave-private rows
    __shared__ float lds_dist[2][64];
    __shared__ float lds_env[2][64];
    __shared__ float lds_unit[2][64][3];

    const int tid  = threadIdx.x;
    const int lane = tid & 63;
    const int w    = tid >> 6;       // wave 0..3
    const int lq   = lane >> 4;      // quad 0..3
    const int lc   = lane & 15;
    const int seg  = blockIdx.x;

    const int st  = start[seg];
    const int cnt = counts[seg];

    // staging assignment: 4 lanes per row, wave-private rows
    const int  R   = w * 16 + (lane >> 2);   // tile row this thread stages
    const int  sq  = lane & 3;               // quarter of the row
    const bool geo = (lane < 16);            // geometry lanes
    const int  G   = w * 16 + (lane & 15);   // geometry row (valid when geo)

    // zero per-wave accumulators + stage biases (only cross-wave init)
    for (int i = tid; i < 4 * 512; i += 256) lds_acc[i] = 0.0f;
    for (int i = tid; i < 896; i += 256)
        lds_bias[i] = (i < 384) ? b2[i] : (i < 768 ? br[i - 384] : b1[i - 768]);

    const bf16x8* W1f = reinterpret_cast<const bf16x8*>(W1p);
    const bf16x8* W2f = reinterpret_cast<const bf16x8*>(W2p);
    const bf16x8* Wrf = reinterpret_cast<const bf16x8*>(Wrp);

    __syncthreads();   // lds_acc + lds_bias visible; ONLY barrier before epilogue

    const int nT = (cnt + 63) >> 6;

    // ---- prologue: stage tile 0 (S rows + geometry buffer 0) ----
    if (nT > 0) {
        const int valid0 = min(64, cnt);
        {
            const int e0 = order[st + min(R, valid0 - 1)];
            const float4* src = reinterpret_cast<const float4*>(
                s_i + (size_t)e0 * FEATN + sq * 32);
            short* dst = lds_sh + R * LSTR + sq * 32;
#pragma unroll
            for (int c = 0; c < 8; ++c) {
                float4 v = src[c];
                unsigned int p0 = (unsigned int)f2bf(v.x) | ((unsigned int)f2bf(v.y) << 16);
                unsigned int p1 = (unsigned int)f2bf(v.z) | ((unsigned int)f2bf(v.w) << 16);
                *reinterpret_cast<uint2*>(dst + c * 4) = make_uint2(p0, p1);
            }
        }
        if (geo) {
            const int e0 = order[st + min(G, valid0 - 1)];
            float gx = r_iI[(size_t)e0 * 3 + 0];
            float gy = r_iI[(size_t)e0 * 3 + 1];
            float gz = r_iI[(size_t)e0 * 3 + 2];
            float d = sqrtf(gx * gx + gy * gy + gz * gz + 3e-8f);
            float inv_d = 1.0f / d;
            lds_dist[0][G] = d;
            lds_unit[0][G][0] = gx * inv_d;
            lds_unit[0][G][1] = gy * inv_d;
            lds_unit[0][G][2] = gz * inv_d;
            float env = (d < CUTF) ? 0.5f * (__cosf(PI_F * d / CUTF) + 1.0f) : 0.0f;
            lds_env[0][G] = (G < valid0) ? env : 0.0f;
            lds_eid[0][G] = e0;
        }
    }

    for (int t = 0; t < nT; ++t) {
        const int  p  = t & 1;
        const bool pf = (t + 1 < nT);

        // ---- A: GEMM1 A-fragments from current S tile ----
        bf16x8 a1[4];
#pragma unroll
        for (int kt = 0; kt < 4; ++kt)
            a1[kt] = *reinterpret_cast<const bf16x8*>(
                lds_sh + (w * 16 + lc) * LSTR + kt * 32 + lq * 8);

        // ---- B: issue next-tile id/geometry loads (consumed at F) ----
        int eR = 0, eG = 0, validn = 0;
        float gx = 0.f, gy = 0.f, gz = 0.f;
        if (pf) {
            validn = min(64, cnt - (t + 1) * 64);
            const int basen = st + (t + 1) * 64;
            eR = order[basen + min(R, validn - 1)];
            if (geo) {
                eG = order[basen + min(G, validn - 1)];
                gx = r_iI[(size_t)eG * 3 + 0];
                gy = r_iI[(size_t)eG * 3 + 1];
                gz = r_iI[(size_t)eG * 3 + 2];
            }
        }

        // ---- C: GEMM1: H = silu(S @ W1 + b1), written in-place (wave rows) ----
#pragma unroll
        for (int nt = 0; nt < 8; ++nt) {
            f32x4 acc = {0.f, 0.f, 0.f, 0.f};
#pragma unroll
            for (int kt = 0; kt < 4; ++kt)
                acc = __builtin_amdgcn_mfma_f32_16x16x32_bf16(
                    a1[kt], W1f[(kt * 8 + nt) * 64 + lane], acc, 0, 0, 0);
            float b1v = lds_bias[768 + nt * 16 + lc];
#pragma unroll
            for (int i = 0; i < 4; ++i) {
                float x = acc[i] + b1v;
                float h = x / (1.0f + __expf(-x));
                lds_sh[(w * 16 + lq * 4 + i) * LSTR + nt * 16 + lc] = (short)f2bf(h);
            }
        }

        // ---- D: GEMM2 A-fragments, rbf fragment, v offsets, first v load ----
        bf16x8 a2[4];
#pragma unroll
        for (int kt = 0; kt < 4; ++kt)
            a2[kt] = *reinterpret_cast<const bf16x8*>(
                lds_sh + (w * 16 + lc) * LSTR + kt * 32 + lq * 8);

        bf16x8 rb;
        {
            float d = lds_dist[p][w * 16 + lc];
            float inv_d = 1.0f / d;
            float x0 = PI_F * d / CUTF;
#pragma unroll
            for (int j = 0; j < 8; ++j) {
                int k = lq * 8 + j;
                float v = 0.0f;
                if (k < NRBF) v = __sinf((float)(k + 1) * x0) * inv_d;
                rb[j] = (short)f2bf(v);
            }
        }

        unsigned voff[4];
#pragma unroll
        for (int i = 0; i < 4; ++i)
            voff[i] = (unsigned)lds_eid[p][w * 16 + lq * 4 + i] * 1536u;

#define LOADV(VX, VY, VZ, ftv)                                               \
        if ((ftv) < 8) {                                                     \
            const int f_ = (ftv) * 16 + lc;                                  \
            _Pragma("unroll")                                                \
            for (int i_ = 0; i_ < 4; ++i_) {                                 \
                const float* vp_ = (const float*)((const char*)v_i +         \
                                                  voff[i_] + f_ * 12);       \
                VX[i_] = vp_[0]; VY[i_] = vp_[1]; VZ[i_] = vp_[2];           \
            }                                                                \
        }

        float vAx[4], vAy[4], vAz[4], vBx[4], vBy[4], vBz[4];
        LOADV(vAx, vAy, vAz, 0)          // flies during F's staging work

        // ---- F: stage next tile (S rows + geometry buffer p^1) ----
        if (pf) {
            {
                const float4* src = reinterpret_cast<const float4*>(
                    s_i + (size_t)eR * FEATN + sq * 32);
                short* dst = lds_sh + R * LSTR + sq * 32;
#pragma unroll
                for (int c = 0; c < 8; ++c) {
                    float4 v = src[c];
                    unsigned int p0 = (unsigned int)f2bf(v.x) | ((unsigned int)f2bf(v.y) << 16);
                    unsigned int p1 = (unsigned int)f2bf(v.z) | ((unsigned int)f2bf(v.w) << 16);
                    *reinterpret_cast<uint2*>(dst + c * 4) = make_uint2(p0, p1);
                }
            }
            if (geo) {
                const int pn = p ^ 1;
                float d = sqrtf(gx * gx + gy * gy + gz * gz + 3e-8f);
                float inv_d = 1.0f / d;
                lds_dist[pn][G] = d;
                lds_unit[pn][G][0] = gx * inv_d;
                lds_unit[pn][G][1] = gy * inv_d;
                lds_unit[pn][G][2] = gz * inv_d;
                float env = (d < CUTF) ? 0.5f * (__cosf(PI_F * d / CUTF) + 1.0f) : 0.0f;
                lds_env[pn][G] = (G < validn) ? env : 0.0f;
                lds_eid[pn][G] = eG;
            }
        }

        // ---- E: GEMM2 + RBF + epilogue, v_i ping-pong prefetch ----
        float* aw = lds_acc + w * 512;

#define FTBODY(ftv, VX, VY, VZ) {                                            \
            const int ft_ = (ftv);                                           \
            f32x4 acc0 = {0.f,0.f,0.f,0.f}, acc1 = {0.f,0.f,0.f,0.f},        \
                  acc2 = {0.f,0.f,0.f,0.f};                                  \
            __builtin_amdgcn_s_setprio(1);                                   \
            _Pragma("unroll")                                                \
            for (int kt_ = 0; kt_ < 4; ++kt_) {                              \
                bf16x8 a_ = a2[kt_];                                         \
                acc0 = __builtin_amdgcn_mfma_f32_16x16x32_bf16(              \
                    a_, W2f[(kt_ * 24 + ft_     ) * 64 + lane], acc0, 0,0,0);\
                acc1 = __builtin_amdgcn_mfma_f32_16x16x32_bf16(              \
                    a_, W2f[(kt_ * 24 + ft_ +  8) * 64 + lane], acc1, 0,0,0);\
                acc2 = __builtin_amdgcn_mfma_f32_16x16x32_bf16(              \
                    a_, W2f[(kt_ * 24 + ft_ + 16) * 64 + lane], acc2, 0,0,0);\
            }                                                                \
            f32x4 z4 = {0.f,0.f,0.f,0.f};                                    \
            f32x4 wa0 = __builtin_amdgcn_mfma_f32_16x16x32_bf16(             \
                rb, Wrf[(ft_     ) * 64 + lane], z4, 0, 0, 0);               \
            f32x4 wa1 = __builtin_amdgcn_mfma_f32_16x16x32_bf16(             \
                rb, Wrf[(ft_ +  8) * 64 + lane], z4, 0, 0, 0);               \
            f32x4 wa2 = __builtin_amdgcn_mfma_f32_16x16x32_bf16(             \
                rb, Wrf[(ft_ + 16) * 64 + lane], z4, 0, 0, 0);               \
            __builtin_amdgcn_s_setprio(0);                                   \
            const int f_ = ft_ * 16 + lc;                                    \
            float b2v0 = lds_bias[f_], b2v1 = lds_bias[128 + f_],            \
                  b2v2 = lds_bias[256 + f_];                                 \
            float brv0 = lds_bias[384 + f_], brv1 = lds_bias[512 + f_],      \
                  brv2 = lds_bias[640 + f_];                                 \
            float sds = 0.f, svx = 0.f, svy = 0.f, svz = 0.f;                \
            _Pragma("unroll")                                                \
            for (int i_ = 0; i_ < 4; ++i_) {                                 \
                const int e_ = w * 16 + lq * 4 + i_;                         \
                const float env_ = lds_env[p][e_];                           \
                float phi0 = acc0[i_] + b2v0;                                \
                float phi1 = acc1[i_] + b2v1;                                \
                float phi2 = acc2[i_] + b2v2;                                \
                float w0 = (wa0[i_] + brv0) * env_;                          \
                float w1 = (wa1[i_] + brv1) * env_;                          \
                float w2 = (wa2[i_] + brv2) * env_;                          \
                float inv0 = phi0 * w0;                                      \
                float inv1 = phi1 * w1;                                      \
                float inv2 = phi2 * w2;                                      \
                sds += inv1;                                                 \
                svx += inv2 * lds_unit[p][e_][0] + inv0 * VX[i_];            \
                svy += inv2 * lds_unit[p][e_][1] + inv0 * VY[i_];            \
                svz += inv2 * lds_unit[p][e_][2] + inv0 * VZ[i_];            \
            }                                                                \
            sds += __shfl_xor(sds, 16); sds += __shfl_xor(sds, 32);          \
            svx += __shfl_xor(svx, 16); svx += __shfl_xor(svx, 32);          \
            svy += __shfl_xor(svy, 16); svy += __shfl_xor(svy, 32);          \
            svz += __shfl_xor(svz, 16); svz += __shfl_xor(svz, 32);          \
            if (lq == 0) {                                                   \
                aw[f_]               += sds;                                 \
                aw[128 + f_ * 3 + 0] += svx;                                 \
                aw[128 + f_ * 3 + 1] += svy;                                 \
                aw[128 + f_ * 3 + 2] += svz;                                 \
            }                                                                \
        }

#pragma unroll 1
        for (int fp = 0; fp < 4; ++fp) {
            const int ft0 = fp * 2;
            LOADV(vBx, vBy, vBz, ft0 + 1)
            FTBODY(ft0, vAx, vAy, vAz)
            LOADV(vAx, vAy, vAz, ft0 + 2)
            FTBODY(ft0 + 1, vBx, vBy, vBz)
        }
#undef LOADV
#undef FTBODY
    }
    __syncthreads();

    // ---- final: cross-wave reduce, mean, write out ----
    const float invc = (cnt > 0) ? (1.0f / (float)cnt) : 0.0f;
    const int NS = NCG * 128;
    for (int o = tid; o < 512; o += 256) {
        float v = lds_acc[o] + lds_acc[512 + o] + lds_acc[1024 + o] + lds_acc[1536 + o];
        v *= invc;
        if (o < 128) out[(size_t)seg * 128 + o] = v;
        else         out[NS + (size_t)seg * 384 + (o - 128)] = v;
    }
}

extern "C" void kernel_launch(void* const* d_in, const int* in_sizes, int n_in,
                              void* d_out, int out_size, void* d_ws, size_t ws_size,
                              hipStream_t stream) {
    const float* s_i  = (const float*)d_in[0];
    const float* v_i  = (const float*)d_in[1];
    const float* r_iI = (const float*)d_in[2];
    const float* W1   = (const float*)d_in[3];
    const float* b1   = (const float*)d_in[4];
    const float* W2   = (const float*)d_in[5];
    const float* b2   = (const float*)d_in[6];
    const float* Wr   = (const float*)d_in[7];
    const float* br   = (const float*)d_in[8];
    const int* mapping = (const int*)d_in[9];
    // d_in[10] = num_cg (compile-time NCG=2000)

    const int E = in_sizes[0] / FEATN;   // 200000

    char* ws = (char*)d_ws;
    int*   counts = (int*)(ws + 0);          //  8,000 B
    int*   start  = (int*)(ws + 8192);       //  8,000 B
    int*   cursor = (int*)(ws + 16384);      //  8,000 B
    int*   order  = (int*)(ws + 24576);      // 800,000 B
    short* W1p    = (short*)(ws + 829440);   // 32,768 B
    short* W2p    = (short*)(ws + 862208);   // 98,304 B
    short* Wrp    = (short*)(ws + 960512);   // 24,576 B

    hipMemsetAsync(counts, 0, NCG * sizeof(int), stream);
    pack_weights<<<(W1P_ELEMS + W2P_ELEMS + WRP_ELEMS) / 256, 256, 0, stream>>>(
        W1, W2, Wr, W1p, W2p, Wrp);
    hist_kernel<<<(E + 255) / 256, 256, 0, stream>>>(mapping, counts, E);
    scan_kernel<<<1, 64, 0, stream>>>(counts, start, cursor);
    scatter_kernel<<<(E + 255) / 256, 256, 0, stream>>>(mapping, cursor, order, E);
    main_kernel<<<NCG, 256, 0, stream>>>(s_i, v_i, r_iI, b1, b2, br,
                                         order, start, counts,
                                         W1p, W2p, Wrp, (float*)d_out);
}